// Round 3
// baseline (1633.293 us; speedup 1.0000x reference)
//
#include <hip/hip_runtime.h>
#include <cstddef>

// Fixed problem instance
#define D_FEAT 128
static constexpr int N_NODES = 100000;
static constexpr int N_EDGES = 20000;
static constexpr int N_INC   = 800000;

typedef unsigned short u16;
typedef unsigned int   u32;

__device__ __forceinline__ float b2f(u16 u) {
    return __uint_as_float(((u32)u) << 16);
}

// ---------------------------------------------------------------------------
// 0a) input-dtype probe: flag=1 if x looks like fp32, 0 if packed bf16.
// Low u16 of each u32 word: bf16-packed -> a real N(0,1) bf16 (exponent
// ~[113,130]); fp32 -> mantissa bits (uniform exponent). Count implausibles.
__global__ __launch_bounds__(256) void probe_dtype(
    const u32* __restrict__ xw, int* __restrict__ flag)
{
    __shared__ int cnt;
    const int tid = threadIdx.x;
    if (tid == 0) cnt = 0;
    __syncthreads();
    const int NW = 2048;
    int bad = 0;
    for (int i = tid; i < NW; i += 256) {
        u32 v = xw[i] & 0xFFFFu;
        int e = (int)((v >> 7) & 0xFF);
        if (v != 0u && (e < 100 || e > 140)) bad++;
    }
    atomicAdd(&cnt, bad);
    __syncthreads();
    if (tid == 0) *flag = (cnt > NW / 8) ? 1 : 0;
}

// ---------------------------------------------------------------------------
// 0b) explicit zeroing
__global__ __launch_bounds__(256) void zero_f32(float* __restrict__ p, int n)
{
    int i = blockIdx.x * 256 + threadIdx.x;
    if (i < n) p[i] = 0.0f;
}

// ---------------------------------------------------------------------------
// 1) degree histogram
__global__ __launch_bounds__(256) void degree_kernel(
    const int* __restrict__ ni, const int* __restrict__ ei,
    float* __restrict__ d_n, float* __restrict__ d_e, int I)
{
    int i = blockIdx.x * 256 + threadIdx.x;
    if (i < I) {
        atomicAdd(&d_n[ni[i]], 1.0f);
        atomicAdd(&d_e[ei[i]], 1.0f);
    }
}

// ---------------------------------------------------------------------------
// 2) xn = (x @ W^T + b) * inv_sqrt_dn ; dtype-adaptive input reads.
// 256 threads = 2 rows x 128 cols per block.
__global__ __launch_bounds__(256) void linear_kernel(
    const void* __restrict__ xv, const void* __restrict__ Wv, const void* __restrict__ bv,
    const float* __restrict__ d_n, const int* __restrict__ flag,
    float* __restrict__ xn)
{
    __shared__ float xrow[2 * D_FEAT];
    const int tid = threadIdx.x;
    const int r   = tid >> 7;          // 0..1
    const int c   = tid & 127;         // 0..127
    const int row = blockIdx.x * 2 + r;
    const int isF32 = *flag;           // wave-uniform

    const u16*   xb = (const u16*)xv;
    const float* xf = (const float*)xv;
    const u16*   Wb = (const u16*)Wv;
    const float* Wf = (const float*)Wv;
    const u16*   bb = (const u16*)bv;
    const float* bf = (const float*)bv;

    size_t xo = (size_t)row * D_FEAT + c;
    xrow[tid] = isF32 ? xf[xo] : b2f(xb[xo]);
    __syncthreads();

    float acc = 0.f;
    size_t wbase = (size_t)c * D_FEAT;
    if (isF32) {
        #pragma unroll 8
        for (int k = 0; k < D_FEAT; ++k)
            acc = fmaf(xrow[r * D_FEAT + k], Wf[wbase + k], acc);
    } else {
        #pragma unroll 8
        for (int k = 0; k < D_FEAT; ++k)
            acc = fmaf(xrow[r * D_FEAT + k], b2f(Wb[wbase + k]), acc);
    }

    const float bias = isF32 ? bf[c] : b2f(bb[c]);
    const float dn = d_n[row];
    const float s  = (dn > 0.f) ? rsqrtf(dn) : 0.f;
    xn[(size_t)row * D_FEAT + c] = (acc + bias) * s;
}

// ---------------------------------------------------------------------------
// 3) node -> edge: e_feat[e,f] += xn[n,f]
__global__ __launch_bounds__(256) void scatter_n2e(
    const int* __restrict__ ni, const int* __restrict__ ei,
    const float* __restrict__ xn, float* __restrict__ e_feat)
{
    size_t gid = (size_t)blockIdx.x * 256 + threadIdx.x;   // < N_INC*128
    int i = (int)(gid >> 7);
    int f = (int)(gid & 127);
    int n = ni[i];
    int e = ei[i];
    atomicAdd(&e_feat[(size_t)e * D_FEAT + f], xn[(size_t)n * D_FEAT + f]);
}

// ---------------------------------------------------------------------------
// 4) edge -> node: y[n,f] += e_feat[e,f] / d_e[e]
__global__ __launch_bounds__(256) void scatter_e2n(
    const int* __restrict__ ni, const int* __restrict__ ei,
    const float* __restrict__ e_feat, const float* __restrict__ d_e,
    float* __restrict__ y)
{
    size_t gid = (size_t)blockIdx.x * 256 + threadIdx.x;
    int i = (int)(gid >> 7);
    int f = (int)(gid & 127);
    int e = ei[i];
    int n = ni[i];
    float inv = 1.0f / d_e[e];   // e appears in ei => d_e[e] >= 1
    atomicAdd(&y[(size_t)n * D_FEAT + f], e_feat[(size_t)e * D_FEAT + f] * inv);
}

// ---------------------------------------------------------------------------
// 5) out_fp32 = relu(y * inv_sqrt_dn)
__global__ __launch_bounds__(256) void finalize_kernel(
    const float* __restrict__ y, const float* __restrict__ d_n,
    float* __restrict__ out)
{
    int gid = blockIdx.x * 256 + threadIdx.x;   // < N_NODES*128
    int n = gid >> 7;
    float dn = d_n[n];
    float s  = (dn > 0.f) ? rsqrtf(dn) : 0.f;
    float v  = y[gid] * s;
    out[gid] = (v > 0.f) ? v : 0.f;
}

// ---------------------------------------------------------------------------
extern "C" void kernel_launch(void* const* d_in, const int* in_sizes, int n_in,
                              void* d_out, int out_size, void* d_ws, size_t ws_size,
                              hipStream_t stream)
{
    const void* x  = d_in[0];              // (N,128)   bf16 or fp32
    const void* W  = d_in[1];              // (128,128) bf16 or fp32
    const void* b  = d_in[2];              // (128,)    bf16 or fp32
    const int* ni  = (const int*)d_in[3];  // (800000,) node_idx
    const int* ei  = (const int*)d_in[4];  // (800000,) edge_idx
    float* out = (float*)d_out;            // fp32 (N,128) — reference output dtype

    // Workspace (fp32 elements):
    //   xn / y : N*128 = 12,800,000   (aliased; xn dead after n2e)
    //   e_feat : E*128 =  2,560,000
    //   d_n    : N     =    100,000
    //   d_e    : E     =     20,000
    //   flag   : 1 int
    float* xn_y   = (float*)d_ws;
    float* e_feat = xn_y + (size_t)N_NODES * D_FEAT;
    float* d_n    = e_feat + (size_t)N_EDGES * D_FEAT;
    float* d_e    = d_n + N_NODES;
    int*   flag   = (int*)(d_e + N_EDGES);

    probe_dtype<<<1, 256, 0, stream>>>((const u32*)x, flag);

    const int zero1 = N_EDGES * D_FEAT + N_NODES + N_EDGES;  // e_feat + d_n + d_e
    zero_f32<<<(zero1 + 255) / 256, 256, 0, stream>>>(e_feat, zero1);

    degree_kernel<<<(N_INC + 255) / 256, 256, 0, stream>>>(ni, ei, d_n, d_e, N_INC);

    linear_kernel<<<N_NODES / 2, 256, 0, stream>>>(x, W, b, d_n, flag, xn_y);

    scatter_n2e<<<(unsigned)((size_t)N_INC * D_FEAT / 256), 256, 0, stream>>>(ni, ei, xn_y, e_feat);

    // xn dead; reuse as y
    const int zero2 = N_NODES * D_FEAT;
    zero_f32<<<(zero2 + 255) / 256, 256, 0, stream>>>(xn_y, zero2);

    scatter_e2n<<<(unsigned)((size_t)N_INC * D_FEAT / 256), 256, 0, stream>>>(ni, ei, e_feat, d_e, xn_y);

    finalize_kernel<<<N_NODES * D_FEAT / 256, 256, 0, stream>>>(xn_y, d_n, out);
}

// Round 6
// 1597.058 us; speedup vs baseline: 1.0227x; 1.0227x over previous
//
#include <hip/hip_runtime.h>
#include <cstddef>

// Fixed problem instance
#define D_FEAT 128
static constexpr int N_NODES = 100000;
static constexpr int N_EDGES = 20000;
static constexpr int N_INC   = 800000;

typedef unsigned short u16;
typedef unsigned int   u32;

__device__ __forceinline__ float b2f(u16 u) {
    return __uint_as_float(((u32)u) << 16);
}

// ---------------------------------------------------------------------------
// 0a) input-dtype probe: flag=1 if x looks like fp32, 0 if packed bf16.
__global__ __launch_bounds__(256) void probe_dtype(
    const u32* __restrict__ xw, int* __restrict__ flag)
{
    __shared__ int cnt;
    const int tid = threadIdx.x;
    if (tid == 0) cnt = 0;
    __syncthreads();
    const int NW = 2048;
    int bad = 0;
    for (int i = tid; i < NW; i += 256) {
        u32 v = xw[i] & 0xFFFFu;
        int e = (int)((v >> 7) & 0xFF);
        if (v != 0u && (e < 100 || e > 140)) bad++;
    }
    atomicAdd(&cnt, bad);
    __syncthreads();
    if (tid == 0) *flag = (cnt > NW / 8) ? 1 : 0;
}

// ---------------------------------------------------------------------------
// 0b) explicit zeroing
__global__ __launch_bounds__(256) void zero_f32(float* __restrict__ p, int n)
{
    int i = blockIdx.x * 256 + threadIdx.x;
    if (i < n) p[i] = 0.0f;
}

// ---------------------------------------------------------------------------
// 1) degree histogram
__global__ __launch_bounds__(256) void degree_kernel(
    const int* __restrict__ ni, const int* __restrict__ ei,
    float* __restrict__ d_n, float* __restrict__ d_e, int I)
{
    int i = blockIdx.x * 256 + threadIdx.x;
    if (i < I) {
        atomicAdd(&d_n[ni[i]], 1.0f);
        atomicAdd(&d_e[ei[i]], 1.0f);
    }
}

// ---------------------------------------------------------------------------
// 2) xn = (x @ W^T + b) * inv_sqrt_dn — LDS-staged W (the r3 linear was the
// measured bottleneck: 770us, VALUBusy 8%, scalar global W reads).
// Block: 256 thr = 8 rows x 32 col-lanes; thread handles cols {cg,cg+32,cg+64,cg+96}.
// LDS W layout: u32 word (k*64 + w) packs bf16 of W[w][k] (lo) and W[w+64][k] (hi)
// => inner-loop reads words cg and cg+32: all 32 banks, conflict-free, r broadcasts.
__global__ __launch_bounds__(256) void linear_fused(
    const void* __restrict__ xv, const void* __restrict__ Wv, const void* __restrict__ bv,
    const float* __restrict__ d_n, const int* __restrict__ flag,
    float* __restrict__ xn)
{
    __shared__ u32  Wt32[128 * 64];   // 32 KB
    __shared__ float xr[8][128];      // 4 KB

    const int tid = threadIdx.x;
    const int rowBase = blockIdx.x * 8;
    const int isF32 = *flag;          // uniform across grid

    if (!isF32) {
        // ---- stage W packed: c = tid>>1 (0..127), k-half = (tid&1)*64
        {
            const u16* Wb = (const u16*)Wv;
            u16* Wt = (u16*)Wt32;
            const int c  = tid >> 1;
            const int k0 = (tid & 1) * 64;
            const int ci = ((c & 63) << 1) + (c >> 6);   // halfword slot within k-row
            const u32* wrow = (const u32*)(Wb + (size_t)c * 128) + (k0 >> 1);
            for (int j = 0; j < 32; ++j) {
                u32 v = wrow[j];                          // W[c][k], W[c][k+1]
                int k = k0 + 2 * j;
                Wt[k * 128 + ci]       = (u16)(v & 0xFFFFu);
                Wt[(k + 1) * 128 + ci] = (u16)(v >> 16);
            }
        }
        // ---- stage 8 x-rows as f32 (512 packed u32 words)
        {
            const u32* xw = (const u32*)xv;
            for (int idx = tid; idx < 512; idx += 256) {
                int r = idx >> 6, wi = idx & 63;
                u32 v = xw[(size_t)(rowBase + r) * 64 + wi];
                xr[r][2 * wi]     = __uint_as_float(v << 16);
                xr[r][2 * wi + 1] = __uint_as_float(v & 0xFFFF0000u);
            }
        }
        __syncthreads();

        const int r  = tid >> 5;   // 0..7
        const int cg = tid & 31;   // 0..31
        float a0 = 0.f, a1 = 0.f, a2 = 0.f, a3 = 0.f;
        #pragma unroll 4
        for (int k = 0; k < 128; ++k) {
            float xval = xr[r][k];                 // broadcast
            u32 w0 = Wt32[k * 64 + cg];            // cols cg (lo), cg+64 (hi)
            u32 w1 = Wt32[k * 64 + cg + 32];       // cols cg+32 (lo), cg+96 (hi)
            a0 = fmaf(xval, __uint_as_float(w0 << 16),          a0);
            a2 = fmaf(xval, __uint_as_float(w0 & 0xFFFF0000u),  a2);
            a1 = fmaf(xval, __uint_as_float(w1 << 16),          a1);
            a3 = fmaf(xval, __uint_as_float(w1 & 0xFFFF0000u),  a3);
        }

        const u16* bb = (const u16*)bv;
        const int row = rowBase + r;
        const float dn = d_n[row];
        const float s  = (dn > 0.f) ? rsqrtf(dn) : 0.f;
        float* orow = xn + (size_t)row * D_FEAT;
        orow[cg]      = (a0 + b2f(bb[cg]))      * s;
        orow[cg + 32] = (a1 + b2f(bb[cg + 32])) * s;
        orow[cg + 64] = (a2 + b2f(bb[cg + 64])) * s;
        orow[cg + 96] = (a3 + b2f(bb[cg + 96])) * s;
    } else {
        // ---- fp32 fallback (correct, not fast; expected dead path)
        const float* xf = (const float*)xv;
        const float* Wf = (const float*)Wv;
        const float* bf = (const float*)bv;
        for (int idx = tid; idx < 1024; idx += 256) {
            int r = idx >> 7, k = idx & 127;
            xr[r][k] = xf[(size_t)(rowBase + r) * D_FEAT + k];
        }
        __syncthreads();
        const int r  = tid >> 5;
        const int cg = tid & 31;
        float a[4] = {0.f, 0.f, 0.f, 0.f};
        for (int k = 0; k < 128; ++k) {
            float xval = xr[r][k];
            #pragma unroll
            for (int t = 0; t < 4; ++t)
                a[t] = fmaf(xval, Wf[(size_t)(cg + 32 * t) * D_FEAT + k], a[t]);
        }
        const int row = rowBase + r;
        const float dn = d_n[row];
        const float s  = (dn > 0.f) ? rsqrtf(dn) : 0.f;
        float* orow = xn + (size_t)row * D_FEAT;
        #pragma unroll
        for (int t = 0; t < 4; ++t)
            orow[cg + 32 * t] = (a[t] + bf[cg + 32 * t]) * s;
    }
}

// ---------------------------------------------------------------------------
// 3) node -> edge: e_feat[e,f] += xn[n,f]
__global__ __launch_bounds__(256) void scatter_n2e(
    const int* __restrict__ ni, const int* __restrict__ ei,
    const float* __restrict__ xn, float* __restrict__ e_feat)
{
    size_t gid = (size_t)blockIdx.x * 256 + threadIdx.x;   // < N_INC*128
    int i = (int)(gid >> 7);
    int f = (int)(gid & 127);
    int n = ni[i];
    int e = ei[i];
    atomicAdd(&e_feat[(size_t)e * D_FEAT + f], xn[(size_t)n * D_FEAT + f]);
}

// ---------------------------------------------------------------------------
// 4) edge -> node: y[n,f] += e_feat[e,f] / d_e[e]
__global__ __launch_bounds__(256) void scatter_e2n(
    const int* __restrict__ ni, const int* __restrict__ ei,
    const float* __restrict__ e_feat, const float* __restrict__ d_e,
    float* __restrict__ y)
{
    size_t gid = (size_t)blockIdx.x * 256 + threadIdx.x;
    int i = (int)(gid >> 7);
    int f = (int)(gid & 127);
    int e = ei[i];
    int n = ni[i];
    float inv = 1.0f / d_e[e];   // e appears in ei => d_e[e] >= 1
    atomicAdd(&y[(size_t)n * D_FEAT + f], e_feat[(size_t)e * D_FEAT + f] * inv);
}

// ---------------------------------------------------------------------------
// 5) out_fp32 = relu(y * inv_sqrt_dn)
__global__ __launch_bounds__(256) void finalize_kernel(
    const float* __restrict__ y, const float* __restrict__ d_n,
    float* __restrict__ out)
{
    int gid = blockIdx.x * 256 + threadIdx.x;   // < N_NODES*128
    int n = gid >> 7;
    float dn = d_n[n];
    float s  = (dn > 0.f) ? rsqrtf(dn) : 0.f;
    float v  = y[gid] * s;
    out[gid] = (v > 0.f) ? v : 0.f;
}

// ---------------------------------------------------------------------------
extern "C" void kernel_launch(void* const* d_in, const int* in_sizes, int n_in,
                              void* d_out, int out_size, void* d_ws, size_t ws_size,
                              hipStream_t stream)
{
    const void* x  = d_in[0];              // (N,128)   bf16 (probe-verified) or fp32
    const void* W  = d_in[1];              // (128,128)
    const void* b  = d_in[2];              // (128,)
    const int* ni  = (const int*)d_in[3];  // (800000,) node_idx
    const int* ei  = (const int*)d_in[4];  // (800000,) edge_idx
    float* out = (float*)d_out;            // fp32 (N,128)

    // Workspace (fp32 elements) — identical to the r3-passing layout:
    float* xn_y   = (float*)d_ws;                          // N*128 (aliased xn/y)
    float* e_feat = xn_y + (size_t)N_NODES * D_FEAT;       // E*128
    float* d_n    = e_feat + (size_t)N_EDGES * D_FEAT;     // N
    float* d_e    = d_n + N_NODES;                         // E
    int*   flag   = (int*)(d_e + N_EDGES);

    probe_dtype<<<1, 256, 0, stream>>>((const u32*)x, flag);

    const int zero1 = N_EDGES * D_FEAT + N_NODES + N_EDGES;  // e_feat + d_n + d_e
    zero_f32<<<(zero1 + 255) / 256, 256, 0, stream>>>(e_feat, zero1);

    degree_kernel<<<(N_INC + 255) / 256, 256, 0, stream>>>(ni, ei, d_n, d_e, N_INC);

    linear_fused<<<N_NODES / 8, 256, 0, stream>>>(x, W, b, d_n, flag, xn_y);

    scatter_n2e<<<(unsigned)((size_t)N_INC * D_FEAT / 256), 256, 0, stream>>>(ni, ei, xn_y, e_feat);

    // xn dead; reuse as y
    const int zero2 = N_NODES * D_FEAT;
    zero_f32<<<(zero2 + 255) / 256, 256, 0, stream>>>(xn_y, zero2);

    scatter_e2n<<<(unsigned)((size_t)N_INC * D_FEAT / 256), 256, 0, stream>>>(ni, ei, e_feat, d_e, xn_y);

    finalize_kernel<<<N_NODES * D_FEAT / 256, 256, 0, stream>>>(xn_y, d_n, out);
}

// Round 7
// 1178.998 us; speedup vs baseline: 1.3853x; 1.3546x over previous
//
#include <hip/hip_runtime.h>
#include <cstddef>

// Fixed problem instance
#define D_FEAT 128
static constexpr int N_NODES = 100000;
static constexpr int N_EDGES = 20000;
static constexpr int N_INC   = 800000;
static constexpr int N_CNT   = N_NODES + N_EDGES;          // combined histogram size
static constexpr int NBLK    = (N_CNT + 255) / 256;        // 469 scan blocks
static constexpr int N_TILES = N_NODES / 8;                // 12500 row-tiles for linear

typedef unsigned short u16;
typedef unsigned int   u32;

__device__ __forceinline__ float b2f(u16 u) {
    return __uint_as_float(((u32)u) << 16);
}

// ---------------------------------------------------------------------------
// 0a) input-dtype probe: flag=1 if x looks like fp32, 0 if packed bf16.
__global__ __launch_bounds__(256) void probe_dtype(
    const u32* __restrict__ xw, int* __restrict__ flag)
{
    __shared__ int cnt;
    const int tid = threadIdx.x;
    if (tid == 0) cnt = 0;
    __syncthreads();
    const int NW = 2048;
    int bad = 0;
    for (int i = tid; i < NW; i += 256) {
        u32 v = xw[i] & 0xFFFFu;
        int e = (int)((v >> 7) & 0xFF);
        if (v != 0u && (e < 100 || e > 140)) bad++;
    }
    atomicAdd(&cnt, bad);
    __syncthreads();
    if (tid == 0) *flag = (cnt > NW / 8) ? 1 : 0;
}

// ---------------------------------------------------------------------------
__global__ __launch_bounds__(256) void zero_int(int* __restrict__ p, int n)
{
    int i = blockIdx.x * 256 + threadIdx.x;
    if (i < n) p[i] = 0;
}

// 1) combined degree histogram: cnt[node] and cnt[N_NODES+edge]
__global__ __launch_bounds__(256) void count_kernel(
    const int* __restrict__ ni, const int* __restrict__ ei,
    int* __restrict__ cnt)
{
    int i = blockIdx.x * 256 + threadIdx.x;
    if (i < N_INC) {
        atomicAdd(&cnt[ni[i]], 1);
        atomicAdd(&cnt[N_NODES + ei[i]], 1);
    }
}

// ---------------------------------------------------------------------------
// 2a) per-block exclusive scan of cnt -> cur (local), block totals -> bsum
//     LDS Hillis-Steele; no shuffles.
__global__ __launch_bounds__(256) void scanA(
    const int* __restrict__ cnt, int* __restrict__ cur, int* __restrict__ bsum)
{
    __shared__ int s[256];
    const int tid = threadIdx.x;
    const int i = blockIdx.x * 256 + tid;
    int v = (i < N_CNT) ? cnt[i] : 0;
    s[tid] = v;
    __syncthreads();
    #pragma unroll
    for (int d = 1; d < 256; d <<= 1) {
        int t = (tid >= d) ? s[tid - d] : 0;
        __syncthreads();
        s[tid] += t;
        __syncthreads();
    }
    if (i < N_CNT) cur[i] = s[tid] - v;          // exclusive, block-local
    if (tid == 0) bsum[blockIdx.x] = s[255];     // block total
}

// 2b) single-block exclusive scan of bsum[NBLK] (chunked, carry in LDS)
__global__ __launch_bounds__(256) void scanB(int* __restrict__ a, int n)
{
    __shared__ int s[256];
    __shared__ int carry;
    const int tid = threadIdx.x;
    if (tid == 0) carry = 0;
    __syncthreads();
    for (int base = 0; base < n; base += 256) {
        int i = base + tid;
        int v = (i < n) ? a[i] : 0;
        s[tid] = v;
        __syncthreads();
        #pragma unroll
        for (int d = 1; d < 256; d <<= 1) {
            int t = (tid >= d) ? s[tid - d] : 0;
            __syncthreads();
            s[tid] += t;
            __syncthreads();
        }
        int excl = s[tid] - v + carry;           // consume carry into register
        int total = s[255];
        __syncthreads();                          // everyone read carry/s
        if (tid == 0) carry += total;
        if (i < n) a[i] = excl;
        __syncthreads();                          // before s/carry reuse
    }
}

// 2c) add block offsets: cur[i] += bsum[block]
__global__ __launch_bounds__(256) void scanC(
    int* __restrict__ cur, const int* __restrict__ bsum)
{
    int i = blockIdx.x * 256 + threadIdx.x;
    if (i < N_CNT) cur[i] += bsum[blockIdx.x];
}

// ---------------------------------------------------------------------------
// 3) fill CSR buckets (int atomics on cursors; cur becomes end-offsets)
__global__ __launch_bounds__(256) void fill_kernel(
    const int* __restrict__ ni, const int* __restrict__ ei,
    int* __restrict__ cur, int* __restrict__ bkt_n, int* __restrict__ bkt_e)
{
    int i = blockIdx.x * 256 + threadIdx.x;
    if (i < N_INC) {
        int n = ni[i], e = ei[i];
        bkt_n[atomicAdd(&cur[n], 1)] = e;                       // node -> its edges
        bkt_e[atomicAdd(&cur[N_NODES + e], 1) - N_INC] = n;     // edge -> its nodes
    }
}

// ---------------------------------------------------------------------------
// 4) xn = (x @ W^T + b) * rsqrt(deg_n), xn lives in d_out (fp32).
// Persistent blocks (1024 = 4/CU): W staged ONCE per block, grid-stride over
// row-tiles. r6's per-tile W re-stage was the 723us bottleneck (64 cachelines
// per staging wave-load through TA; 12500 re-stagings). Inner loop unchanged.
__global__ __launch_bounds__(256) void linear_fused(
    const void* __restrict__ xv, const void* __restrict__ Wv, const void* __restrict__ bv,
    const int* __restrict__ cnt, const int* __restrict__ flag,
    float* __restrict__ xn)
{
    __shared__ u32  Wt32[128 * 64];   // 32 KB packed: word k*64+w = {W[w][k], W[w+64][k]}
    __shared__ float xr[8][128];      // 4 KB

    const int tid = threadIdx.x;
    const int isF32 = *flag;          // uniform across grid

    if (!isF32) {
        {   // ---- stage W packed (once per block)
            const u16* Wb = (const u16*)Wv;
            u16* Wt = (u16*)Wt32;
            const int c  = tid >> 1;
            const int k0 = (tid & 1) * 64;
            const int ci = ((c & 63) << 1) + (c >> 6);
            const u32* wrow = (const u32*)(Wb + (size_t)c * 128) + (k0 >> 1);
            for (int j = 0; j < 32; ++j) {
                u32 v = wrow[j];
                int k = k0 + 2 * j;
                Wt[k * 128 + ci]       = (u16)(v & 0xFFFFu);
                Wt[(k + 1) * 128 + ci] = (u16)(v >> 16);
            }
        }
        const u16* bb = (const u16*)bv;
        const u32* xw = (const u32*)xv;
        const int r  = tid >> 5;   // 0..7
        const int cg = tid & 31;   // 0..31

        for (int tile = blockIdx.x; tile < N_TILES; tile += gridDim.x) {
            const int rowBase = tile * 8;
            for (int idx = tid; idx < 512; idx += 256) {
                int rr = idx >> 6, wi = idx & 63;
                u32 v = xw[(size_t)(rowBase + rr) * 64 + wi];
                xr[rr][2 * wi]     = __uint_as_float(v << 16);
                xr[rr][2 * wi + 1] = __uint_as_float(v & 0xFFFF0000u);
            }
            __syncthreads();

            float a0 = 0.f, a1 = 0.f, a2 = 0.f, a3 = 0.f;
            #pragma unroll 4
            for (int k = 0; k < 128; ++k) {
                float xval = xr[r][k];                 // broadcast
                u32 w0 = Wt32[k * 64 + cg];            // cols cg (lo), cg+64 (hi)
                u32 w1 = Wt32[k * 64 + cg + 32];       // cols cg+32 (lo), cg+96 (hi)
                a0 = fmaf(xval, __uint_as_float(w0 << 16),          a0);
                a2 = fmaf(xval, __uint_as_float(w0 & 0xFFFF0000u),  a2);
                a1 = fmaf(xval, __uint_as_float(w1 << 16),          a1);
                a3 = fmaf(xval, __uint_as_float(w1 & 0xFFFF0000u),  a3);
            }

            const int row = rowBase + r;
            const int cn  = cnt[row];
            const float s = (cn > 0) ? rsqrtf((float)cn) : 0.f;
            float* orow = xn + (size_t)row * D_FEAT;
            orow[cg]      = (a0 + b2f(bb[cg]))      * s;
            orow[cg + 32] = (a1 + b2f(bb[cg + 32])) * s;
            orow[cg + 64] = (a2 + b2f(bb[cg + 64])) * s;
            orow[cg + 96] = (a3 + b2f(bb[cg + 96])) * s;
            __syncthreads();                          // before next xr overwrite
        }
    } else {
        // ---- fp32 fallback (correct, not fast; expected dead path)
        const float* xf = (const float*)xv;
        const float* Wf = (const float*)Wv;
        const float* bf = (const float*)bv;
        const int r  = tid >> 5;
        const int cg = tid & 31;
        for (int tile = blockIdx.x; tile < N_TILES; tile += gridDim.x) {
            const int rowBase = tile * 8;
            for (int idx = tid; idx < 1024; idx += 256) {
                int rr = idx >> 7, k = idx & 127;
                xr[rr][k] = xf[(size_t)(rowBase + rr) * D_FEAT + k];
            }
            __syncthreads();
            float a[4] = {0.f, 0.f, 0.f, 0.f};
            for (int k = 0; k < 128; ++k) {
                float xval = xr[r][k];
                #pragma unroll
                for (int t = 0; t < 4; ++t)
                    a[t] = fmaf(xval, Wf[(size_t)(cg + 32 * t) * D_FEAT + k], a[t]);
            }
            const int row = rowBase + r;
            const int cn  = cnt[row];
            const float s = (cn > 0) ? rsqrtf((float)cn) : 0.f;
            float* orow = xn + (size_t)row * D_FEAT;
            #pragma unroll
            for (int t = 0; t < 4; ++t)
                orow[cg + 32 * t] = (a[t] + bf[cg + 32 * t]) * s;
            __syncthreads();
        }
    }
}

// ---------------------------------------------------------------------------
// 5) per-edge gather: ef[e,:] = (1/|e|) * sum_{n in e} xn[n,:]
// one wave per edge; lane covers features {lane, lane+64} (coalesced 256B).
__global__ __launch_bounds__(256) void n2e_kernel(
    const int* __restrict__ cnt, const int* __restrict__ cur,
    const int* __restrict__ bkt_e, const float* __restrict__ xn,
    float* __restrict__ ef)
{
    const int e    = blockIdx.x * 4 + (threadIdx.x >> 6);
    const int lane = threadIdx.x & 63;
    const int c    = cnt[N_NODES + e];
    if (c == 0) return;                              // row never read downstream
    const int start = cur[N_NODES + e] - c - N_INC;  // cur holds end offsets
    float a0 = 0.f, a1 = 0.f;
    for (int j = 0; j < c; ++j) {
        int n = bkt_e[start + j];                    // wave-broadcast (L1)
        a0 += xn[(size_t)n * D_FEAT + lane];
        a1 += xn[(size_t)n * D_FEAT + 64 + lane];
    }
    float inv = 1.0f / (float)c;
    ef[(size_t)e * D_FEAT + lane]      = a0 * inv;
    ef[(size_t)e * D_FEAT + 64 + lane] = a1 * inv;
}

// ---------------------------------------------------------------------------
// 6) per-node gather + finalize: out[n,:] = relu(rsqrt(deg_n) * sum_e ef[e,:])
__global__ __launch_bounds__(256) void e2n_kernel(
    const int* __restrict__ cnt, const int* __restrict__ cur,
    const int* __restrict__ bkt_n, const float* __restrict__ ef,
    float* __restrict__ out)
{
    const int node = blockIdx.x * 4 + (threadIdx.x >> 6);   // 25000*4 == N_NODES
    const int lane = threadIdx.x & 63;
    const int c    = cnt[node];
    const int start = cur[node] - c;
    float a0 = 0.f, a1 = 0.f;
    for (int j = 0; j < c; ++j) {
        int e = bkt_n[start + j];                    // wave-broadcast (L1)
        a0 += ef[(size_t)e * D_FEAT + lane];
        a1 += ef[(size_t)e * D_FEAT + 64 + lane];
    }
    float s = (c > 0) ? rsqrtf((float)c) : 0.f;
    a0 *= s; a1 *= s;
    out[(size_t)node * D_FEAT + lane]      = (a0 > 0.f) ? a0 : 0.f;
    out[(size_t)node * D_FEAT + 64 + lane] = (a1 > 0.f) ? a1 : 0.f;
}

// ---------------------------------------------------------------------------
extern "C" void kernel_launch(void* const* d_in, const int* in_sizes, int n_in,
                              void* d_out, int out_size, void* d_ws, size_t ws_size,
                              hipStream_t stream)
{
    const void* x  = d_in[0];              // (N,128)   bf16 (probe-verified) or fp32
    const void* W  = d_in[1];              // (128,128)
    const void* b  = d_in[2];              // (128,)
    const int* ni  = (const int*)d_in[3];  // (800000,) node_idx
    const int* ei  = (const int*)d_in[4];  // (800000,) edge_idx
    float* out = (float*)d_out;            // fp32 (N,128)

    // xn is staged IN d_out (written by linear, consumed by n2e, then d_out is
    // fully rewritten by e2n). Workspace (~17.7 MB):
    char* p = (char*)d_ws;
    float* ef   = (float*)p; p += (size_t)N_EDGES * D_FEAT * 4;   // 10.24 MB
    int* cnt    = (int*)p;   p += (size_t)N_CNT * 4;              // 480 KB
    int* cur    = (int*)p;   p += (size_t)N_CNT * 4;              // 480 KB
    int* bsum   = (int*)p;   p += (size_t)((NBLK + 7) & ~7) * 4;
    int* flag   = (int*)p;   p += 16;
    int* bkt_n  = (int*)p;   p += (size_t)N_INC * 4;              // 3.2 MB
    int* bkt_e  = (int*)p;   p += (size_t)N_INC * 4;              // 3.2 MB
    float* xn   = out;

    const int nInc = (N_INC + 255) / 256;

    probe_dtype<<<1, 256, 0, stream>>>((const u32*)x, flag);

    zero_int<<<NBLK, 256, 0, stream>>>(cnt, N_CNT);
    count_kernel<<<nInc, 256, 0, stream>>>(ni, ei, cnt);

    scanA<<<NBLK, 256, 0, stream>>>(cnt, cur, bsum);
    scanB<<<1, 256, 0, stream>>>(bsum, NBLK);
    scanC<<<NBLK, 256, 0, stream>>>(cur, bsum);

    fill_kernel<<<nInc, 256, 0, stream>>>(ni, ei, cur, bkt_n, bkt_e);

    linear_fused<<<1024, 256, 0, stream>>>(x, W, b, cnt, flag, xn);

    n2e_kernel<<<N_EDGES / 4, 256, 0, stream>>>(cnt, cur, bkt_e, xn, ef);

    e2n_kernel<<<N_NODES / 4, 256, 0, stream>>>(cnt, cur, bkt_n, ef, out);
}

// Round 8
// 1172.773 us; speedup vs baseline: 1.3927x; 1.0053x over previous
//
#include <hip/hip_runtime.h>
#include <cstddef>

// Fixed problem instance
#define D_FEAT 128
static constexpr int N_NODES = 100000;
static constexpr int N_EDGES = 20000;
static constexpr int N_INC   = 800000;
static constexpr int N_CNT   = N_NODES + N_EDGES;          // combined histogram size
static constexpr int NBLK    = (N_CNT + 255) / 256;        // 469 scan blocks
static constexpr int N_WTILE = N_NODES / 16;               // 6250 16-row MFMA tiles

typedef unsigned short u16;
typedef unsigned int   u32;
typedef __attribute__((ext_vector_type(8))) short v8s;     // MFMA A/B frag (8 bf16)
typedef __attribute__((ext_vector_type(4))) float v4f;     // MFMA C/D frag

__device__ __forceinline__ float b2f(u16 u) {
    return __uint_as_float(((u32)u) << 16);
}

// ---------------------------------------------------------------------------
// 0a) input-dtype probe: flag=1 if x looks like fp32, 0 if packed bf16.
__global__ __launch_bounds__(256) void probe_dtype(
    const u32* __restrict__ xw, int* __restrict__ flag)
{
    __shared__ int cnt;
    const int tid = threadIdx.x;
    if (tid == 0) cnt = 0;
    __syncthreads();
    const int NW = 2048;
    int bad = 0;
    for (int i = tid; i < NW; i += 256) {
        u32 v = xw[i] & 0xFFFFu;
        int e = (int)((v >> 7) & 0xFF);
        if (v != 0u && (e < 100 || e > 140)) bad++;
    }
    atomicAdd(&cnt, bad);
    __syncthreads();
    if (tid == 0) *flag = (cnt > NW / 8) ? 1 : 0;
}

// ---------------------------------------------------------------------------
__global__ __launch_bounds__(256) void zero_int(int* __restrict__ p, int n)
{
    int i = blockIdx.x * 256 + threadIdx.x;
    if (i < n) p[i] = 0;
}

// 1) combined degree histogram: cnt[node] and cnt[N_NODES+edge]
__global__ __launch_bounds__(256) void count_kernel(
    const int* __restrict__ ni, const int* __restrict__ ei,
    int* __restrict__ cnt)
{
    int i = blockIdx.x * 256 + threadIdx.x;
    if (i < N_INC) {
        atomicAdd(&cnt[ni[i]], 1);
        atomicAdd(&cnt[N_NODES + ei[i]], 1);
    }
}

// ---------------------------------------------------------------------------
// 2a) per-block exclusive scan of cnt -> cur (local), block totals -> bsum
__global__ __launch_bounds__(256) void scanA(
    const int* __restrict__ cnt, int* __restrict__ cur, int* __restrict__ bsum)
{
    __shared__ int s[256];
    const int tid = threadIdx.x;
    const int i = blockIdx.x * 256 + tid;
    int v = (i < N_CNT) ? cnt[i] : 0;
    s[tid] = v;
    __syncthreads();
    #pragma unroll
    for (int d = 1; d < 256; d <<= 1) {
        int t = (tid >= d) ? s[tid - d] : 0;
        __syncthreads();
        s[tid] += t;
        __syncthreads();
    }
    if (i < N_CNT) cur[i] = s[tid] - v;          // exclusive, block-local
    if (tid == 0) bsum[blockIdx.x] = s[255];     // block total
}

// 2b) single-block exclusive scan of bsum[NBLK]
__global__ __launch_bounds__(256) void scanB(int* __restrict__ a, int n)
{
    __shared__ int s[256];
    __shared__ int carry;
    const int tid = threadIdx.x;
    if (tid == 0) carry = 0;
    __syncthreads();
    for (int base = 0; base < n; base += 256) {
        int i = base + tid;
        int v = (i < n) ? a[i] : 0;
        s[tid] = v;
        __syncthreads();
        #pragma unroll
        for (int d = 1; d < 256; d <<= 1) {
            int t = (tid >= d) ? s[tid - d] : 0;
            __syncthreads();
            s[tid] += t;
            __syncthreads();
        }
        int excl = s[tid] - v + carry;
        int total = s[255];
        __syncthreads();
        if (tid == 0) carry += total;
        if (i < n) a[i] = excl;
        __syncthreads();
    }
}

// 2c) add block offsets
__global__ __launch_bounds__(256) void scanC(
    int* __restrict__ cur, const int* __restrict__ bsum)
{
    int i = blockIdx.x * 256 + threadIdx.x;
    if (i < N_CNT) cur[i] += bsum[blockIdx.x];
}

// ---------------------------------------------------------------------------
// 3) fill CSR buckets (cur becomes end-offsets)
__global__ __launch_bounds__(256) void fill_kernel(
    const int* __restrict__ ni, const int* __restrict__ ei,
    int* __restrict__ cur, int* __restrict__ bkt_n, int* __restrict__ bkt_e)
{
    int i = blockIdx.x * 256 + threadIdx.x;
    if (i < N_INC) {
        int n = ni[i], e = ei[i];
        bkt_n[atomicAdd(&cur[n], 1)] = e;                       // node -> its edges
        bkt_e[atomicAdd(&cur[N_NODES + e], 1) - N_INC] = n;     // edge -> its nodes
    }
}

// ---------------------------------------------------------------------------
// 4) xn = (x @ W^T + b) * rsqrt(deg_n), xn lives in d_out (fp32). MFMA version.
// The r3/r6/r7 VALU linears all hit ~725us: a 128-deep dependent ds_read->fma
// chain per thread is LDS-latency serialized (~150cyc/step) and 12-16 waves/CU
// can't hide it. MFMA replaces 32 chain steps with one instruction.
// Wave tile: 16 rows x 128 cols. A-frag: lane(m=lane&15,quad=lane>>4) holds
// x[rowBase+m][ks*32+quad*8 ..+7]; B-frag: W[t*16+m][ks*32+quad*8 ..+7]
// (out = x.W^T is exactly the verified gemm_bt pattern, m97).
// C/D: col=lane&15, row=quad*4+reg (m89/m91-verified).
__global__ __launch_bounds__(256) void linear_mfma(
    const u16* __restrict__ x, const u16* __restrict__ W, const u16* __restrict__ b,
    const int* __restrict__ cnt, const int* __restrict__ flag,
    float* __restrict__ xn)
{
    if (*flag) return;                              // fp32 path handled by fallback
    const int wave = threadIdx.x >> 6;
    const int lane = threadIdx.x & 63;
    const int rowBase = (blockIdx.x * 4 + wave) * 16;
    if (rowBase >= N_NODES) return;                 // tail waves idle (no barriers here)
    const int m    = lane & 15;
    const int quad = lane >> 4;

    v4f acc[8];
    #pragma unroll
    for (int t = 0; t < 8; ++t) acc[t] = (v4f){0.f, 0.f, 0.f, 0.f};

    #pragma unroll
    for (int ks = 0; ks < 4; ++ks) {
        const int k0 = ks * 32 + quad * 8;
        v8s af = *(const v8s*)(x + (size_t)(rowBase + m) * D_FEAT + k0);
        #pragma unroll
        for (int t = 0; t < 8; ++t) {
            v8s bfr = *(const v8s*)(W + (size_t)(t * 16 + m) * D_FEAT + k0);
            acc[t] = __builtin_amdgcn_mfma_f32_16x16x32_bf16(af, bfr, acc[t], 0, 0, 0);
        }
    }

    // row scales for this lane's quad (4 consecutive rows), scalar int loads
    const int rq = rowBase + quad * 4;
    const int c0 = cnt[rq + 0], c1 = cnt[rq + 1], c2 = cnt[rq + 2], c3 = cnt[rq + 3];
    const float s0 = (c0 > 0) ? rsqrtf((float)c0) : 0.f;
    const float s1 = (c1 > 0) ? rsqrtf((float)c1) : 0.f;
    const float s2 = (c2 > 0) ? rsqrtf((float)c2) : 0.f;
    const float s3 = (c3 > 0) ? rsqrtf((float)c3) : 0.f;

    #pragma unroll
    for (int t = 0; t < 8; ++t) {
        const int col = t * 16 + m;
        const float bias = b2f(b[col]);
        float* o = xn + (size_t)rq * D_FEAT + col;
        o[0 * D_FEAT] = (acc[t][0] + bias) * s0;
        o[1 * D_FEAT] = (acc[t][1] + bias) * s1;
        o[2 * D_FEAT] = (acc[t][2] + bias) * s2;
        o[3 * D_FEAT] = (acc[t][3] + bias) * s3;
    }
}

// 4b) fp32-input fallback (dead when flag==0; cheap early-out otherwise)
__global__ __launch_bounds__(256) void linear_f32(
    const float* __restrict__ xf, const float* __restrict__ Wf, const float* __restrict__ bf,
    const int* __restrict__ cnt, const int* __restrict__ flag,
    float* __restrict__ xn)
{
    if (!*flag) return;
    __shared__ float xr[8][128];
    const int tid = threadIdx.x;
    const int rowBase = blockIdx.x * 8;
    for (int idx = tid; idx < 1024; idx += 256) {
        int rr = idx >> 7, k = idx & 127;
        xr[rr][k] = xf[(size_t)(rowBase + rr) * D_FEAT + k];
    }
    __syncthreads();
    const int r  = tid >> 5;
    const int cg = tid & 31;
    float a[4] = {0.f, 0.f, 0.f, 0.f};
    for (int k = 0; k < 128; ++k) {
        float xval = xr[r][k];
        #pragma unroll
        for (int t = 0; t < 4; ++t)
            a[t] = fmaf(xval, Wf[(size_t)(cg + 32 * t) * D_FEAT + k], a[t]);
    }
    const int row = rowBase + r;
    const int cn  = cnt[row];
    const float s = (cn > 0) ? rsqrtf((float)cn) : 0.f;
    float* orow = xn + (size_t)row * D_FEAT;
    #pragma unroll
    for (int t = 0; t < 4; ++t)
        orow[cg + 32 * t] = (a[t] + bf[cg + 32 * t]) * s;
}

// ---------------------------------------------------------------------------
// 5) per-edge gather: ef[e,:] = (1/|e|) * sum_{n in e} xn[n,:]
__global__ __launch_bounds__(256) void n2e_kernel(
    const int* __restrict__ cnt, const int* __restrict__ cur,
    const int* __restrict__ bkt_e, const float* __restrict__ xn,
    float* __restrict__ ef)
{
    const int e    = blockIdx.x * 4 + (threadIdx.x >> 6);
    const int lane = threadIdx.x & 63;
    const int c    = cnt[N_NODES + e];
    if (c == 0) return;                              // row never read downstream
    const int start = cur[N_NODES + e] - c - N_INC;  // cur holds end offsets
    float a0 = 0.f, a1 = 0.f;
    for (int j = 0; j < c; ++j) {
        int n = bkt_e[start + j];                    // wave-broadcast (L1)
        a0 += xn[(size_t)n * D_FEAT + lane];
        a1 += xn[(size_t)n * D_FEAT + 64 + lane];
    }
    float inv = 1.0f / (float)c;
    ef[(size_t)e * D_FEAT + lane]      = a0 * inv;
    ef[(size_t)e * D_FEAT + 64 + lane] = a1 * inv;
}

// ---------------------------------------------------------------------------
// 6) per-node gather + finalize: out[n,:] = relu(rsqrt(deg_n) * sum_e ef[e,:])
__global__ __launch_bounds__(256) void e2n_kernel(
    const int* __restrict__ cnt, const int* __restrict__ cur,
    const int* __restrict__ bkt_n, const float* __restrict__ ef,
    float* __restrict__ out)
{
    const int node = blockIdx.x * 4 + (threadIdx.x >> 6);   // 25000*4 == N_NODES
    const int lane = threadIdx.x & 63;
    const int c    = cnt[node];
    const int start = cur[node] - c;
    float a0 = 0.f, a1 = 0.f;
    for (int j = 0; j < c; ++j) {
        int e = bkt_n[start + j];                    // wave-broadcast (L1)
        a0 += ef[(size_t)e * D_FEAT + lane];
        a1 += ef[(size_t)e * D_FEAT + 64 + lane];
    }
    float s = (c > 0) ? rsqrtf((float)c) : 0.f;
    a0 *= s; a1 *= s;
    out[(size_t)node * D_FEAT + lane]      = (a0 > 0.f) ? a0 : 0.f;
    out[(size_t)node * D_FEAT + 64 + lane] = (a1 > 0.f) ? a1 : 0.f;
}

// ---------------------------------------------------------------------------
extern "C" void kernel_launch(void* const* d_in, const int* in_sizes, int n_in,
                              void* d_out, int out_size, void* d_ws, size_t ws_size,
                              hipStream_t stream)
{
    const void* x  = d_in[0];              // (N,128)   bf16 (probe-verified) or fp32
    const void* W  = d_in[1];              // (128,128)
    const void* b  = d_in[2];              // (128,)
    const int* ni  = (const int*)d_in[3];  // (800000,) node_idx
    const int* ei  = (const int*)d_in[4];  // (800000,) edge_idx
    float* out = (float*)d_out;            // fp32 (N,128)

    // xn staged IN d_out (linear writes, n2e consumes, e2n overwrites).
    char* p = (char*)d_ws;
    float* ef   = (float*)p; p += (size_t)N_EDGES * D_FEAT * 4;   // 10.24 MB
    int* cnt    = (int*)p;   p += (size_t)N_CNT * 4;
    int* cur    = (int*)p;   p += (size_t)N_CNT * 4;
    int* bsum   = (int*)p;   p += (size_t)((NBLK + 7) & ~7) * 4;
    int* flag   = (int*)p;   p += 16;
    int* bkt_n  = (int*)p;   p += (size_t)N_INC * 4;              // 3.2 MB
    int* bkt_e  = (int*)p;   p += (size_t)N_INC * 4;              // 3.2 MB
    float* xn   = out;

    const int nInc = (N_INC + 255) / 256;

    probe_dtype<<<1, 256, 0, stream>>>((const u32*)x, flag);

    zero_int<<<NBLK, 256, 0, stream>>>(cnt, N_CNT);
    count_kernel<<<nInc, 256, 0, stream>>>(ni, ei, cnt);

    scanA<<<NBLK, 256, 0, stream>>>(cnt, cur, bsum);
    scanB<<<1, 256, 0, stream>>>(bsum, NBLK);
    scanC<<<NBLK, 256, 0, stream>>>(cur, bsum);

    fill_kernel<<<nInc, 256, 0, stream>>>(ni, ei, cur, bkt_n, bkt_e);

    linear_mfma<<<(N_WTILE + 3) / 4, 256, 0, stream>>>(
        (const u16*)x, (const u16*)W, (const u16*)b, cnt, flag, xn);
    linear_f32<<<N_NODES / 8, 256, 0, stream>>>(
        (const float*)x, (const float*)W, (const float*)b, cnt, flag, xn);

    n2e_kernel<<<N_EDGES / 4, 256, 0, stream>>>(cnt, cur, bkt_e, xn, ef);

    e2n_kernel<<<N_NODES / 4, 256, 0, stream>>>(cnt, cur, bkt_n, ef, out);
}

// Round 9
// 574.581 us; speedup vs baseline: 2.8426x; 2.0411x over previous
//
#include <hip/hip_runtime.h>
#include <cstddef>

// Fixed problem instance (inputs are fp32 — probe-verified in r8: linear_f32
// executed full-length, reference setup_inputs is jnp.float32 throughout)
#define D_FEAT 128
static constexpr int N_NODES = 100000;
static constexpr int N_EDGES = 20000;
static constexpr int N_INC   = 800000;
static constexpr int N_CNT   = N_NODES + N_EDGES;          // combined histogram size
static constexpr int NBLK    = (N_CNT + 255) / 256;        // 469 scan blocks
static constexpr int N_WTILE = N_NODES / 16;               // 6250 16-row MFMA tiles

typedef unsigned short u16;
typedef unsigned int   u32;
typedef __attribute__((ext_vector_type(8))) short v8s;     // MFMA A/B frag (8 bf16)
typedef __attribute__((ext_vector_type(4))) float v4f;     // MFMA C/D frag

// ---------------------------------------------------------------------------
__global__ __launch_bounds__(256) void zero_int(int* __restrict__ p, int n)
{
    int i = blockIdx.x * 256 + threadIdx.x;
    if (i < n) p[i] = 0;
}

// 1) combined degree histogram: cnt[node] and cnt[N_NODES+edge]
__global__ __launch_bounds__(256) void count_kernel(
    const int* __restrict__ ni, const int* __restrict__ ei,
    int* __restrict__ cnt)
{
    int i = blockIdx.x * 256 + threadIdx.x;
    if (i < N_INC) {
        atomicAdd(&cnt[ni[i]], 1);
        atomicAdd(&cnt[N_NODES + ei[i]], 1);
    }
}

// ---------------------------------------------------------------------------
// 2a) per-block exclusive scan of cnt -> cur (local), block totals -> bsum
__global__ __launch_bounds__(256) void scanA(
    const int* __restrict__ cnt, int* __restrict__ cur, int* __restrict__ bsum)
{
    __shared__ int s[256];
    const int tid = threadIdx.x;
    const int i = blockIdx.x * 256 + tid;
    int v = (i < N_CNT) ? cnt[i] : 0;
    s[tid] = v;
    __syncthreads();
    #pragma unroll
    for (int d = 1; d < 256; d <<= 1) {
        int t = (tid >= d) ? s[tid - d] : 0;
        __syncthreads();
        s[tid] += t;
        __syncthreads();
    }
    if (i < N_CNT) cur[i] = s[tid] - v;          // exclusive, block-local
    if (tid == 0) bsum[blockIdx.x] = s[255];     // block total
}

// 2b) single-block exclusive scan of bsum[NBLK]
__global__ __launch_bounds__(256) void scanB(int* __restrict__ a, int n)
{
    __shared__ int s[256];
    __shared__ int carry;
    const int tid = threadIdx.x;
    if (tid == 0) carry = 0;
    __syncthreads();
    for (int base = 0; base < n; base += 256) {
        int i = base + tid;
        int v = (i < n) ? a[i] : 0;
        s[tid] = v;
        __syncthreads();
        #pragma unroll
        for (int d = 1; d < 256; d <<= 1) {
            int t = (tid >= d) ? s[tid - d] : 0;
            __syncthreads();
            s[tid] += t;
            __syncthreads();
        }
        int excl = s[tid] - v + carry;
        int total = s[255];
        __syncthreads();
        if (tid == 0) carry += total;
        if (i < n) a[i] = excl;
        __syncthreads();
    }
}

// 2c) add block offsets
__global__ __launch_bounds__(256) void scanC(
    int* __restrict__ cur, const int* __restrict__ bsum)
{
    int i = blockIdx.x * 256 + threadIdx.x;
    if (i < N_CNT) cur[i] += bsum[blockIdx.x];
}

// ---------------------------------------------------------------------------
// 3) fill CSR buckets (cur becomes end-offsets)
__global__ __launch_bounds__(256) void fill_kernel(
    const int* __restrict__ ni, const int* __restrict__ ei,
    int* __restrict__ cur, int* __restrict__ bkt_n, int* __restrict__ bkt_e)
{
    int i = blockIdx.x * 256 + threadIdx.x;
    if (i < N_INC) {
        int n = ni[i], e = ei[i];
        bkt_n[atomicAdd(&cur[n], 1)] = e;                       // node -> its edges
        bkt_e[atomicAdd(&cur[N_NODES + e], 1) - N_INC] = n;     // edge -> its nodes
    }
}

// ---------------------------------------------------------------------------
// 4a) Dekker split: v = bf16(hi) + bf16(lo) with residual ~2^-17 rel.
__global__ __launch_bounds__(256) void split_kernel(
    const float* __restrict__ in, u16* __restrict__ hi, u16* __restrict__ lo, int n)
{
    for (int i = blockIdx.x * 256 + threadIdx.x; i < n; i += gridDim.x * 256) {
        float v = in[i];
        u32 uv = __float_as_uint(v);
        u32 h  = (uv + 0x7FFFu + ((uv >> 16) & 1u)) & 0xFFFF0000u;   // bf16 RNE
        float r = v - __uint_as_float(h);                            // exact
        u32 ur = __float_as_uint(r);
        u32 l  = ur + 0x7FFFu + ((ur >> 16) & 1u);
        hi[i] = (u16)(h >> 16);
        lo[i] = (u16)(l >> 16);
    }
}

// ---------------------------------------------------------------------------
// 4b) xn = (x @ W^T + b) * rsqrt(deg_n), fp32-accurate via split-bf16 MFMA:
// x.W^T = xhi.Whi + xhi.Wlo + xlo.Whi  (lo.lo ~2^-18, dropped).
// Wave tile 16 rows x 128 cols; A-frag lane(m,quad) = x[rowBase+m][k0..k0+7],
// B-frag = W[t*16+m][k0..k0+7] (gemm_bt pattern); C/D col=lane&15, row=quad*4+reg.
// r8's executed linear (fp32 VALU, W global loads @512B lane stride) was 726us;
// this replaces the L2-gather wall with 96 MFMAs/wave.
__global__ __launch_bounds__(256) void linear_mfma(
    const u16* __restrict__ xhi, const u16* __restrict__ xlo,
    const u16* __restrict__ Whi, const u16* __restrict__ Wlo,
    const float* __restrict__ bias, const int* __restrict__ cnt,
    float* __restrict__ xn)
{
    const int wave = threadIdx.x >> 6;
    const int lane = threadIdx.x & 63;
    const int rowBase = (blockIdx.x * 4 + wave) * 16;
    if (rowBase >= N_NODES) return;                 // tail waves idle (no barriers)
    const int m    = lane & 15;
    const int quad = lane >> 4;

    v4f acc[8];
    #pragma unroll
    for (int t = 0; t < 8; ++t) acc[t] = (v4f){0.f, 0.f, 0.f, 0.f};

    #pragma unroll
    for (int ks = 0; ks < 4; ++ks) {
        const int k0 = ks * 32 + quad * 8;
        const size_t axo = (size_t)(rowBase + m) * D_FEAT + k0;
        v8s ah = *(const v8s*)(xhi + axo);
        v8s al = *(const v8s*)(xlo + axo);
        #pragma unroll
        for (int t = 0; t < 8; ++t) {
            const size_t bo = (size_t)(t * 16 + m) * D_FEAT + k0;
            v8s bh = *(const v8s*)(Whi + bo);
            v8s bl = *(const v8s*)(Wlo + bo);
            acc[t] = __builtin_amdgcn_mfma_f32_16x16x32_bf16(ah, bh, acc[t], 0, 0, 0);
            acc[t] = __builtin_amdgcn_mfma_f32_16x16x32_bf16(ah, bl, acc[t], 0, 0, 0);
            acc[t] = __builtin_amdgcn_mfma_f32_16x16x32_bf16(al, bh, acc[t], 0, 0, 0);
        }
    }

    const int rq = rowBase + quad * 4;
    const int c0 = cnt[rq + 0], c1 = cnt[rq + 1], c2 = cnt[rq + 2], c3 = cnt[rq + 3];
    const float s0 = (c0 > 0) ? rsqrtf((float)c0) : 0.f;
    const float s1 = (c1 > 0) ? rsqrtf((float)c1) : 0.f;
    const float s2 = (c2 > 0) ? rsqrtf((float)c2) : 0.f;
    const float s3 = (c3 > 0) ? rsqrtf((float)c3) : 0.f;

    #pragma unroll
    for (int t = 0; t < 8; ++t) {
        const int col = t * 16 + m;
        const float bv = bias[col];
        float* o = xn + (size_t)rq * D_FEAT + col;
        o[0 * D_FEAT] = (acc[t][0] + bv) * s0;
        o[1 * D_FEAT] = (acc[t][1] + bv) * s1;
        o[2 * D_FEAT] = (acc[t][2] + bv) * s2;
        o[3 * D_FEAT] = (acc[t][3] + bv) * s3;
    }
}

// ---------------------------------------------------------------------------
// 5) per-edge gather: ef[e,:] = (1/|e|) * sum_{n in e} xn[n,:]
__global__ __launch_bounds__(256) void n2e_kernel(
    const int* __restrict__ cnt, const int* __restrict__ cur,
    const int* __restrict__ bkt_e, const float* __restrict__ xn,
    float* __restrict__ ef)
{
    const int e    = blockIdx.x * 4 + (threadIdx.x >> 6);
    const int lane = threadIdx.x & 63;
    const int c    = cnt[N_NODES + e];
    if (c == 0) return;                              // row never read downstream
    const int start = cur[N_NODES + e] - c - N_INC;  // cur holds end offsets
    float a0 = 0.f, a1 = 0.f;
    for (int j = 0; j < c; ++j) {
        int n = bkt_e[start + j];                    // wave-broadcast (L1)
        a0 += xn[(size_t)n * D_FEAT + lane];
        a1 += xn[(size_t)n * D_FEAT + 64 + lane];
    }
    float inv = 1.0f / (float)c;
    ef[(size_t)e * D_FEAT + lane]      = a0 * inv;
    ef[(size_t)e * D_FEAT + 64 + lane] = a1 * inv;
}

// ---------------------------------------------------------------------------
// 6) per-node gather + finalize: out[n,:] = relu(rsqrt(deg_n) * sum_e ef[e,:])
__global__ __launch_bounds__(256) void e2n_kernel(
    const int* __restrict__ cnt, const int* __restrict__ cur,
    const int* __restrict__ bkt_n, const float* __restrict__ ef,
    float* __restrict__ out)
{
    const int node = blockIdx.x * 4 + (threadIdx.x >> 6);   // 25000*4 == N_NODES
    const int lane = threadIdx.x & 63;
    const int c    = cnt[node];
    const int start = cur[node] - c;
    float a0 = 0.f, a1 = 0.f;
    for (int j = 0; j < c; ++j) {
        int e = bkt_n[start + j];                    // wave-broadcast (L1)
        a0 += ef[(size_t)e * D_FEAT + lane];
        a1 += ef[(size_t)e * D_FEAT + 64 + lane];
    }
    float s = (c > 0) ? rsqrtf((float)c) : 0.f;
    a0 *= s; a1 *= s;
    out[(size_t)node * D_FEAT + lane]      = (a0 > 0.f) ? a0 : 0.f;
    out[(size_t)node * D_FEAT + 64 + lane] = (a1 > 0.f) ? a1 : 0.f;
}

// ---------------------------------------------------------------------------
extern "C" void kernel_launch(void* const* d_in, const int* in_sizes, int n_in,
                              void* d_out, int out_size, void* d_ws, size_t ws_size,
                              hipStream_t stream)
{
    const float* x  = (const float*)d_in[0];   // fp32 (N,128)
    const float* W  = (const float*)d_in[1];   // fp32 (128,128)
    const float* b  = (const float*)d_in[2];   // fp32 (128,)
    const int* ni   = (const int*)d_in[3];     // (800000,) node_idx
    const int* ei   = (const int*)d_in[4];     // (800000,) edge_idx
    float* out = (float*)d_out;                // fp32 (N,128)

    // Workspace (~58.6 MB; r1 proved >=61.9 MB available).
    // Region A (51.2 MB) holds xhi+xlo during the linear; ef ALIASES it
    // afterwards (xhi/xlo dead once linear completes, n2e then writes ef).
    char* base = (char*)d_ws;
    u16*   xhi  = (u16*)base;                                  // 25.6 MB
    u16*   xlo  = (u16*)(base + (size_t)N_NODES * D_FEAT * 2); // 25.6 MB
    float* ef   = (float*)base;                                // aliases region A
    char* p = base + (size_t)N_NODES * D_FEAT * 4;             // end of region A
    int* cnt    = (int*)p;   p += (size_t)N_CNT * 4;
    int* cur    = (int*)p;   p += (size_t)N_CNT * 4;
    int* bsum   = (int*)p;   p += (size_t)((NBLK + 7) & ~7) * 4;
    u16* Whi    = (u16*)p;   p += (size_t)D_FEAT * D_FEAT * 2; // 32 KB
    u16* Wlo    = (u16*)p;   p += (size_t)D_FEAT * D_FEAT * 2; // 32 KB
    int* bkt_n  = (int*)p;   p += (size_t)N_INC * 4;           // 3.2 MB
    int* bkt_e  = (int*)p;   p += (size_t)N_INC * 4;           // 3.2 MB
    float* xn   = out;   // xn staged in d_out (linear writes, n2e reads, e2n overwrites)

    const int nInc = (N_INC + 255) / 256;

    zero_int<<<NBLK, 256, 0, stream>>>(cnt, N_CNT);
    count_kernel<<<nInc, 256, 0, stream>>>(ni, ei, cnt);

    scanA<<<NBLK, 256, 0, stream>>>(cnt, cur, bsum);
    scanB<<<1, 256, 0, stream>>>(bsum, NBLK);
    scanC<<<NBLK, 256, 0, stream>>>(cur, bsum);

    fill_kernel<<<nInc, 256, 0, stream>>>(ni, ei, cur, bkt_n, bkt_e);

    split_kernel<<<1024, 256, 0, stream>>>(x, xhi, xlo, N_NODES * D_FEAT);
    split_kernel<<<64, 256, 0, stream>>>(W, Whi, Wlo, D_FEAT * D_FEAT);

    linear_mfma<<<(N_WTILE + 3) / 4, 256, 0, stream>>>(
        xhi, xlo, Whi, Wlo, b, cnt, xn);

    n2e_kernel<<<N_EDGES / 4, 256, 0, stream>>>(cnt, cur, bkt_e, xn, ef);

    e2n_kernel<<<N_NODES / 4, 256, 0, stream>>>(cnt, cur, bkt_n, ef, out);
}